// Round 3
// baseline (227.173 us; speedup 1.0000x reference)
//
#include <hip/hip_runtime.h>
#include <math.h>

#define NCH  256
#define CROP 7

typedef float v4f __attribute__((ext_vector_type(4)));

__device__ __forceinline__ float lerpf(float a, float b, float t) {
    return a + (b - a) * t;
}

// One block per ROI: 512 threads = 8 waves; each wave handles one output
// pixel across all 256 channels (64 lanes x float4), marching pix += 8
// (7 iterations).
//
// Locality: all 49 pixels of an ROI bilinear-sample a small neighborhood of
// one fm level -> keeping the whole ROI on one CU makes corner overlap
// L1/L2-hit (Round 2). Occupancy: 8 waves/block doubles resident waves vs
// 4-wave blocks (1000 blocks x 8 = 8000 waves ~ 24-31/CU) to hide the
// ~900-cyc cold-miss latency (harness fill thrashes L3 between reps).
__global__ __launch_bounds__(512, 6) void roialign_fpn_kernel(
    const float* __restrict__ p2, const float* __restrict__ p3,
    const float* __restrict__ p4, const float* __restrict__ p5,
    const float* __restrict__ rois, const int* __restrict__ bidx,
    float* __restrict__ out, int N)
{
    const int tid = threadIdx.x;
    const int cv  = tid & 63;            // channel quad index: c = 4*cv
    const int pl  = tid >> 6;            // wave id 0..7 (uniform per wave)
    const int n   = blockIdx.x;

    // ROI box [x1,y1,x2,y2] in image coords (uniform -> scalar loads)
    const float rx1 = rois[4*n+0];
    const float ry1 = rois[4*n+1];
    const float rx2 = rois[4*n+2];
    const float ry2 = rois[4*n+3];
    const float w = rx2 - rx1;
    const float h = ry2 - ry1;

    // level = clip(round(log2(sqrt(h*w)/224) + 4), 2, 5)
    // KEEP BIT-IDENTICAL to the verified version (level flips would blow absmax).
    const float lvlf = logf(sqrtf(h * w) / 224.0f) / logf(2.0f) + 4.0f;
    int lvl = (int)rintf(lvlf);
    lvl = lvl < 2 ? 2 : (lvl > 5 ? 5 : lvl);
    const int i = lvl - 2;               // 0..3 -> p2..p5, stride 4<<i

    const int H = 256 >> i;              // square maps
    const float* fm = (i == 0) ? p2 : (i == 1) ? p3 : (i == 2) ? p4 : p5;
    const float inv = 1.0f / (float)((4 << i) * H);  // (roi/stride)/H, exact pow2
    const float Hm1 = (float)(H - 1);

    const float ny1 = ry1 * inv, ny2 = ry2 * inv;
    const float nx1 = rx1 * inv, nx2 = rx2 * inv;

    const int b = bidx[n];
    const size_t bbase = (size_t)b * H;
    const int c = cv * 4;
    float* outn = out + (size_t)n * (CROP * CROP * NCH) + c;

    // Fused second tuple output: batch_indices as float at the flat tail.
    if (tid == 0)
        out[(size_t)N * (CROP * CROP * NCH) + n] = (float)b;

    #pragma unroll 2
    for (int pix = pl; pix < CROP * CROP; pix += 8) {
        const int jy = pix / CROP;
        const int jx = pix - jy * CROP;

        // g = j/6.0 (float division to match np bit-for-bit)
        const float gy = (float)jy / 6.0f;
        const float gx = (float)jx / 6.0f;
        const float in_y = (ny1 + (ny2 - ny1) * gy) * Hm1;
        const float in_x = (nx1 + (nx2 - nx1) * gx) * Hm1;

        const bool valid = (in_y >= 0.0f) && (in_y <= Hm1) &&
                           (in_x >= 0.0f) && (in_x <= Hm1);

        const float y0f = floorf(in_y);
        const float x0f = floorf(in_x);
        const float ly = in_y - y0f;
        const float lx = in_x - x0f;
        const int y0 = (int)fminf(fmaxf(y0f,          0.0f), Hm1);
        const int y1 = (int)fminf(fmaxf(ceilf(in_y),  0.0f), Hm1);
        const int x0 = (int)fminf(fmaxf(x0f,          0.0f), Hm1);
        const int x1 = (int)fminf(fmaxf(ceilf(in_x),  0.0f), Hm1);

        const size_t row0 = (bbase + y0) * (size_t)H;
        const size_t row1 = (bbase + y1) * (size_t)H;

        const v4f tl = *(const v4f*)(fm + (row0 + x0) * NCH + c);
        const v4f tr = *(const v4f*)(fm + (row0 + x1) * NCH + c);
        const v4f bl = *(const v4f*)(fm + (row1 + x0) * NCH + c);
        const v4f br = *(const v4f*)(fm + (row1 + x1) * NCH + c);

        v4f r;
        r.x = lerpf(lerpf(tl.x, tr.x, lx), lerpf(bl.x, br.x, lx), ly);
        r.y = lerpf(lerpf(tl.y, tr.y, lx), lerpf(bl.y, br.y, lx), ly);
        r.z = lerpf(lerpf(tl.z, tr.z, lx), lerpf(bl.z, br.z, lx), ly);
        r.w = lerpf(lerpf(tl.w, tr.w, lx), lerpf(bl.w, br.w, lx), ly);
        if (!valid) { r.x = 0.0f; r.y = 0.0f; r.z = 0.0f; r.w = 0.0f; }

        // Output has zero reuse -> nontemporal store keeps L2 for fm reads.
        __builtin_nontemporal_store(r, (v4f*)(outn + (size_t)pix * NCH));
    }
}

extern "C" void kernel_launch(void* const* d_in, const int* in_sizes, int n_in,
                              void* d_out, int out_size, void* d_ws, size_t ws_size,
                              hipStream_t stream) {
    const float* p2   = (const float*)d_in[0];
    const float* p3   = (const float*)d_in[1];
    const float* p4   = (const float*)d_in[2];
    const float* p5   = (const float*)d_in[3];
    const float* rois = (const float*)d_in[4];
    const int*   bidx = (const int*)d_in[5];
    float* out = (float*)d_out;

    const int N = in_sizes[5];           // number of ROIs

    roialign_fpn_kernel<<<dim3(N), 512, 0, stream>>>(p2, p3, p4, p5, rois, bidx,
                                                     out, N);
}

// Round 4
// 222.231 us; speedup vs baseline: 1.0222x; 1.0222x over previous
//
#include <hip/hip_runtime.h>
#include <math.h>

#define NCH  256
#define CROP 7

typedef float v4f __attribute__((ext_vector_type(4)));

__device__ __forceinline__ float lerpf(float a, float b, float t) {
    return a + (b - a) * t;
}

// Best-measured structure (session min 224.77 us): grid = (13, N), one block
// = 4 output pixels x 64 channel-quads. Three structurally disjoint variants
// (13K-block, 1K x 4-wave ROI-local, 1K x 8-wave) all tie within +-1%: the
// kernel sits at its unique cold-fetch + write floor (~85-135 MB fm reads,
// L3 flushed by the harness's 512 MiB re-poison fills, + 50 MB writes).
// This round: reclaim the best grid shape and fold the bidx tail write into
// an otherwise-idle wave slot (pix == 49), eliminating the second dispatch.
__global__ __launch_bounds__(256) void roialign_fpn_kernel(
    const float* __restrict__ p2, const float* __restrict__ p3,
    const float* __restrict__ p4, const float* __restrict__ p5,
    const float* __restrict__ rois, const int* __restrict__ bidx,
    float* __restrict__ out, int N)
{
    const int tid = threadIdx.x;
    const int cv  = tid & 63;            // channel quad index: c = 4*cv
    const int pl  = tid >> 6;            // 0..3
    const int pix = blockIdx.x * 4 + pl; // 0..51 (49..51 idle slots)
    const int n   = blockIdx.y;

    if (pix >= CROP * CROP) {
        // Fused second tuple output on an idle wave slot of the last block.
        if (pix == CROP * CROP && cv == 0)
            out[(size_t)N * (CROP * CROP * NCH) + n] = (float)bidx[n];
        return;
    }
    const int jy = pix / CROP;
    const int jx = pix - jy * CROP;

    // ROI box [x1,y1,x2,y2] in image coords
    const float rx1 = rois[4*n+0];
    const float ry1 = rois[4*n+1];
    const float rx2 = rois[4*n+2];
    const float ry2 = rois[4*n+3];
    const float w = rx2 - rx1;
    const float h = ry2 - ry1;

    // level = clip(round(log2(sqrt(h*w)/224) + 4), 2, 5); jnp.round = half-to-even
    // KEEP BIT-IDENTICAL (level flips would blow absmax).
    const float lvlf = logf(sqrtf(h * w) / 224.0f) / logf(2.0f) + 4.0f;
    int lvl = (int)rintf(lvlf);
    lvl = lvl < 2 ? 2 : (lvl > 5 ? 5 : lvl);
    const int i = lvl - 2;               // 0..3 -> p2..p5, stride 4<<i

    const int H = 256 >> i;              // H == W (square maps)
    const float* fm = (i == 0) ? p2 : (i == 1) ? p3 : (i == 2) ? p4 : p5;
    // ref: (roi/stride)/H ; both pow2 divisions -> exact as one reciprocal mul
    const float inv = 1.0f / (float)((4 << i) * H);
    const float Hm1 = (float)(H - 1);

    // g = j/6.0 (float division to match np bit-for-bit)
    const float gy = (float)jy / 6.0f;
    const float gx = (float)jx / 6.0f;
    const float ny1 = ry1 * inv, ny2 = ry2 * inv;
    const float nx1 = rx1 * inv, nx2 = rx2 * inv;
    const float in_y = (ny1 + (ny2 - ny1) * gy) * Hm1;
    const float in_x = (nx1 + (nx2 - nx1) * gx) * Hm1;

    const bool valid = (in_y >= 0.0f) && (in_y <= Hm1) &&
                       (in_x >= 0.0f) && (in_x <= Hm1);

    const float y0f = floorf(in_y);
    const float x0f = floorf(in_x);
    const float ly = in_y - y0f;
    const float lx = in_x - x0f;
    const int y0 = (int)fminf(fmaxf(y0f,          0.0f), Hm1);
    const int y1 = (int)fminf(fmaxf(ceilf(in_y),  0.0f), Hm1);
    const int x0 = (int)fminf(fmaxf(x0f,          0.0f), Hm1);
    const int x1 = (int)fminf(fmaxf(ceilf(in_x),  0.0f), Hm1);

    const int b = bidx[n];
    const size_t row0 = ((size_t)b * H + y0) * (size_t)H;
    const size_t row1 = ((size_t)b * H + y1) * (size_t)H;
    const int c = cv * 4;

    const v4f tl = *(const v4f*)(fm + (row0 + x0) * NCH + c);
    const v4f tr = *(const v4f*)(fm + (row0 + x1) * NCH + c);
    const v4f bl = *(const v4f*)(fm + (row1 + x0) * NCH + c);
    const v4f br = *(const v4f*)(fm + (row1 + x1) * NCH + c);

    v4f r;
    r.x = lerpf(lerpf(tl.x, tr.x, lx), lerpf(bl.x, br.x, lx), ly);
    r.y = lerpf(lerpf(tl.y, tr.y, lx), lerpf(bl.y, br.y, lx), ly);
    r.z = lerpf(lerpf(tl.z, tr.z, lx), lerpf(bl.z, br.z, lx), ly);
    r.w = lerpf(lerpf(tl.w, tr.w, lx), lerpf(bl.w, br.w, lx), ly);
    if (!valid) { r.x = 0.0f; r.y = 0.0f; r.z = 0.0f; r.w = 0.0f; }

    // Output has zero reuse -> nontemporal store keeps L2 for fm reads.
    __builtin_nontemporal_store(r, (v4f*)(out + ((size_t)n * (CROP * CROP) + pix) * NCH + c));
}

extern "C" void kernel_launch(void* const* d_in, const int* in_sizes, int n_in,
                              void* d_out, int out_size, void* d_ws, size_t ws_size,
                              hipStream_t stream) {
    const float* p2   = (const float*)d_in[0];
    const float* p3   = (const float*)d_in[1];
    const float* p4   = (const float*)d_in[2];
    const float* p5   = (const float*)d_in[3];
    const float* rois = (const float*)d_in[4];
    const int*   bidx = (const int*)d_in[5];
    float* out = (float*)d_out;

    const int N = in_sizes[5];           // number of ROIs

    dim3 grid((CROP * CROP + 3) / 4, N); // (13, 1000); block 12 slot pix==49 writes tail
    roialign_fpn_kernel<<<grid, 256, 0, stream>>>(p2, p3, p4, p5, rois, bidx,
                                                  out, N);
}